// Round 1
// baseline (731.463 us; speedup 1.0000x reference)
//
#include <hip/hip_runtime.h>

// PhaseEncoding: out[b,i,j,p] = 1.0f iff bins[p] <= (x[b,i,j] % 2pi) < bins[p+1]
// x in [0, 2pi) fp32, bins = float32 linspace(0, 2pi, 9).
// Memory-bound: 64 MiB read + 512 MiB write -> target ~6 TB/s.

__global__ __launch_bounds__(256) void PhaseEncoding_kernel(
    const float* __restrict__ x,
    const float* __restrict__ bins,
    float* __restrict__ out,
    int n4)  // number of float4 input chunks
{
    // Broadcast-load the 9 bin edges (same address across lanes -> cached, free).
    float b0 = bins[0], b1 = bins[1], b2 = bins[2], b3 = bins[3], b4 = bins[4];
    float b5 = bins[5], b6 = bins[6], b7 = bins[7], b8 = bins[8];

    const float TWO_PI = 6.28318530717958647692f;

    const float4* __restrict__ x4 = reinterpret_cast<const float4*>(x);
    float4* __restrict__ o4 = reinterpret_cast<float4*>(out);

    int stride = gridDim.x * blockDim.x;
    for (int i = blockIdx.x * blockDim.x + threadIdx.x; i < n4; i += stride) {
        float4 xv = x4[i];
        float xs0 = xv.x, xs1 = xv.y, xs2 = xv.z, xs3 = xv.w;
        float xe[4];
        xe[0] = fmodf(xs0, TWO_PI);   // exact; identity for x in [0, 2pi)
        xe[1] = fmodf(xs1, TWO_PI);
        xe[2] = fmodf(xs2, TWO_PI);
        xe[3] = fmodf(xs3, TWO_PI);

        #pragma unroll
        for (int e = 0; e < 4; ++e) {
            float xn = xe[e];
            float4 lo, hi;
            lo.x = (xn >= b0 && xn < b1) ? 1.0f : 0.0f;
            lo.y = (xn >= b1 && xn < b2) ? 1.0f : 0.0f;
            lo.z = (xn >= b2 && xn < b3) ? 1.0f : 0.0f;
            lo.w = (xn >= b3 && xn < b4) ? 1.0f : 0.0f;
            hi.x = (xn >= b4 && xn < b5) ? 1.0f : 0.0f;
            hi.y = (xn >= b5 && xn < b6) ? 1.0f : 0.0f;
            hi.z = (xn >= b6 && xn < b7) ? 1.0f : 0.0f;
            hi.w = (xn >= b7 && xn < b8) ? 1.0f : 0.0f;
            // element (4i+e) owns out float4 slots [8i + 2e, 8i + 2e + 1]
            o4[(size_t)i * 8 + e * 2 + 0] = lo;
            o4[(size_t)i * 8 + e * 2 + 1] = hi;
        }
    }
}

extern "C" void kernel_launch(void* const* d_in, const int* in_sizes, int n_in,
                              void* d_out, int out_size, void* d_ws, size_t ws_size,
                              hipStream_t stream) {
    const float* x = (const float*)d_in[0];
    const float* bins = (const float*)d_in[1];
    float* out = (float*)d_out;

    int n = in_sizes[0];          // 8*4096*512 = 16,777,216 (divisible by 4)
    int n4 = n / 4;

    int block = 256;
    int grid = (n4 + block - 1) / block;
    if (grid > 2048) grid = 2048; // 256 CUs x 8 blocks, grid-stride for the rest

    PhaseEncoding_kernel<<<grid, block, 0, stream>>>(x, bins, out, n4);
}

// Round 3
// 580.198 us; speedup vs baseline: 1.2607x; 1.2607x over previous
//
#include <hip/hip_runtime.h>

// PhaseEncoding: out[b,i,j,p] = 1.0f iff bins[p] <= (x[b,i,j] % 2pi) < bins[p+1]
// x fp32 in [0, 2pi), bins = fp32 linspace(0, 2pi, 9). Output [N][8] fp32.
//
// R1 fix: coalesced writes. Each thread owns ONE output float4 slot g
// (16 B): element g>>1, bins [0..4) if g even else [4..8). Consecutive
// lanes -> consecutive 16 B -> 1 KB contiguous per store instruction.
// Reads x[g>>1]: lane pairs share an address, wave reads 128 B contiguous.

__global__ __launch_bounds__(256) void PhaseEncoding_kernel(
    const float* __restrict__ x,
    const float* __restrict__ bins,
    float4* __restrict__ o4,
    int total4)  // = 2 * nelems
{
    // Uniform address -> scalar loads, broadcast free.
    float b0 = bins[0], b1 = bins[1], b2 = bins[2], b3 = bins[3], b4 = bins[4];
    float b5 = bins[5], b6 = bins[6], b7 = bins[7], b8 = bins[8];

    const float TWO_PI = 6.28318530717958647692f;

    int stride = gridDim.x * blockDim.x;
    for (int g = blockIdx.x * blockDim.x + threadIdx.x; g < total4; g += stride) {
        int elem = g >> 1;
        bool hi = (g & 1) != 0;

        float xn = fmodf(x[elem], TWO_PI);  // identity for x in [0, 2pi); exact for x >= 0

        // This lane's 5 bin edges (lower half or upper half of the 9 edges).
        float e0 = hi ? b4 : b0;
        float e1 = hi ? b5 : b1;
        float e2 = hi ? b6 : b2;
        float e3 = hi ? b7 : b3;
        float e4 = hi ? b8 : b4;

        float4 r;
        r.x = (xn >= e0 && xn < e1) ? 1.0f : 0.0f;
        r.y = (xn >= e1 && xn < e2) ? 1.0f : 0.0f;
        r.z = (xn >= e2 && xn < e3) ? 1.0f : 0.0f;
        r.w = (xn >= e3 && xn < e4) ? 1.0f : 0.0f;

        o4[g] = r;
    }
}

extern "C" void kernel_launch(void* const* d_in, const int* in_sizes, int n_in,
                              void* d_out, int out_size, void* d_ws, size_t ws_size,
                              hipStream_t stream) {
    const float* x = (const float*)d_in[0];
    const float* bins = (const float*)d_in[1];
    float4* o4 = (float4*)d_out;

    int n = in_sizes[0];            // 8*4096*512 = 16,777,216
    int total4 = n * 2;             // output float4 slots (n*8 floats / 4)

    int block = 256;
    int grid = (total4 + block - 1) / block;
    if (grid > 2048) grid = 2048;   // grid-stride the rest (256 CU x 8 blocks)

    PhaseEncoding_kernel<<<grid, block, 0, stream>>>(x, bins, o4, total4);
}

// Round 7
// 576.606 us; speedup vs baseline: 1.2686x; 1.0062x over previous
//
#include <hip/hip_runtime.h>

// PhaseEncoding: out[b,i,j,p] = 1.0f iff bins[p] <= (x[b,i,j] % 2pi) < bins[p+1]
// x fp32 in [0, 2pi), bins = fp32 linspace(0, 2pi, 9). Output [N][8] fp32.
//
// Layout (R1): thread owns ONE output float4 slot g: element g>>1, lower
// 4 bins if g even else upper 4. Consecutive lanes -> consecutive 16 B ->
// 1 KB contiguous per wave store. Reads x[g>>1]: lane pairs share one
// address, wave reads 128 B contiguous.
//
// R4: (a) fmodf -> exact branch-free guard (x>=2pi ? x-2pi : x), exact
// for x in [0,4pi) by Sterbenz; (b) known trip count + unroll 4 so four
// independent load->store chains are in flight (hide ~900cy HBM latency);
// (c) nontemporal loads/stores: all data is touch-once streaming.
// R5: use native ext_vector float4 for the nontemporal builtins (HIP's
// float4 class type is rejected by __builtin_nontemporal_store).

typedef float f32x4 __attribute__((ext_vector_type(4)));

__global__ __launch_bounds__(256) void PhaseEncoding_kernel(
    const float* __restrict__ x,
    const float* __restrict__ bins,
    f32x4* __restrict__ o4,
    int iters, int stride, int total4)
{
    // Uniform address -> scalar loads, broadcast free.
    float b0 = bins[0], b1 = bins[1], b2 = bins[2], b3 = bins[3], b4 = bins[4];
    float b5 = bins[5], b6 = bins[6], b7 = bins[7], b8 = bins[8];

    const float TWO_PI = 6.28318530717958647692f;

    int tid = blockIdx.x * blockDim.x + threadIdx.x;

    #pragma unroll 4
    for (int it = 0; it < iters; ++it) {
        int g = tid + it * stride;
        int elem = g >> 1;
        bool hi = (g & 1) != 0;

        float xs = __builtin_nontemporal_load(&x[elem]);
        // Exact fmod(x, 2pi) for x in [0, 4pi): Sterbenz subtraction.
        float xn = (xs >= TWO_PI) ? (xs - TWO_PI) : xs;

        float e0 = hi ? b4 : b0;
        float e1 = hi ? b5 : b1;
        float e2 = hi ? b6 : b2;
        float e3 = hi ? b7 : b3;
        float e4 = hi ? b8 : b4;

        f32x4 r;
        r.x = (xn >= e0 && xn < e1) ? 1.0f : 0.0f;
        r.y = (xn >= e1 && xn < e2) ? 1.0f : 0.0f;
        r.z = (xn >= e2 && xn < e3) ? 1.0f : 0.0f;
        r.w = (xn >= e3 && xn < e4) ? 1.0f : 0.0f;

        __builtin_nontemporal_store(r, &o4[g]);
    }

    // Tail (empty for the benched shape: total4 = 2^25, stride = 2^19).
    int g = tid + iters * stride;
    if (g < total4) {
        int elem = g >> 1;
        bool hi = (g & 1) != 0;
        float xs = x[elem];
        float xn = (xs >= TWO_PI) ? (xs - TWO_PI) : xs;
        float e0 = hi ? b4 : b0, e1 = hi ? b5 : b1, e2 = hi ? b6 : b2;
        float e3 = hi ? b7 : b3, e4 = hi ? b8 : b4;
        f32x4 r;
        r.x = (xn >= e0 && xn < e1) ? 1.0f : 0.0f;
        r.y = (xn >= e1 && xn < e2) ? 1.0f : 0.0f;
        r.z = (xn >= e2 && xn < e3) ? 1.0f : 0.0f;
        r.w = (xn >= e3 && xn < e4) ? 1.0f : 0.0f;
        o4[g] = r;
    }
}

extern "C" void kernel_launch(void* const* d_in, const int* in_sizes, int n_in,
                              void* d_out, int out_size, void* d_ws, size_t ws_size,
                              hipStream_t stream) {
    const float* x = (const float*)d_in[0];
    const float* bins = (const float*)d_in[1];
    f32x4* o4 = (f32x4*)d_out;

    int n = in_sizes[0];            // 8*4096*512 = 16,777,216
    int total4 = n * 2;             // output float4 slots

    int block = 256;
    int grid = 2048;                // 256 CU x 8 blocks
    int stride = grid * block;      // 524,288
    int iters = total4 / stride;    // 64 for the benched shape

    PhaseEncoding_kernel<<<grid, block, 0, stream>>>(x, bins, o4, iters, stride, total4);
}